// Round 11
// baseline (181.752 us; speedup 1.0000x reference)
//
#include <hip/hip_runtime.h>
#include <math.h>

// Problem constants (B,T,E,H fixed by setup_inputs).
constexpr int B_ = 8, T_ = 2048, E_ = 1024, H_ = 64;
constexpr long BT = (long)B_ * T_;   // 16384 rows

typedef __attribute__((ext_vector_type(8))) short bf16x8;   // 8 bf16 (4 VGPRs)
typedef __attribute__((ext_vector_type(4))) float f32x4;    // MFMA 16x16 acc

__device__ inline unsigned short bf16_rne(float f) {
    union { float f; unsigned u; } v; v.f = f;
    unsigned u = v.u + (0x7FFFu + ((v.u >> 16) & 1u));
    return (unsigned short)(u >> 16);
}
// HW packed fp32->bf16 RNE: 1 VALU inst vs ~6 for the bit-twiddle pair.
__device__ inline unsigned pack_bf16x2(float lo, float hi) {
    unsigned r;
    asm("v_cvt_pk_bf16_f32 %0, %1, %2" : "=v"(r) : "v"(lo), "v"(hi));
    return r;
}

// Async global->LDS DMA, 16B per lane.
__device__ inline void load_lds16(const void* g, void* l) {
    __builtin_amdgcn_global_load_lds(
        (const __attribute__((address_space(1))) void*)(uintptr_t)g,
        (__attribute__((address_space(3))) void*)(unsigned)(uintptr_t)l,
        16, 0, 0);
}

constexpr float QS = 0.18033688011112042f;   // H^-0.5 * log2(e), folded into Wq

// ====================================================================
// Kernel 0: build B-frag-ready transposed bf16 weight buffer. (R3)
// ====================================================================
__global__ __launch_bounds__(256) void wt_build_k(
    const float* __restrict__ Wk, const float* __restrict__ Wq,
    const float* __restrict__ Wv, unsigned short* __restrict__ Wt)
{
    const int d    = blockIdx.x * 256 + threadIdx.x;   // 0..24575
    const int tile = d >> 6;
    const int lq   = d & 63;
    const int quad = lq >> 4;
    const int l16  = lq & 15;
    const int kc   = tile / 12;
    const int nt   = tile - kc * 12;
    const int n    = nt * 16 + l16;

    const float* src; int col; float s = 1.0f;
    if (n < 64)       { src = Wk; col = n; }
    else if (n < 128) { src = Wq; col = n - 64; s = QS; }
    else              { src = Wv; col = n - 128; }

    const int kk0 = kc * 32 + quad * 8;
    const float* sp = src + (size_t)kk0 * H_ + col;
    unsigned p[4];
    #pragma unroll
    for (int jj = 0; jj < 4; jj++)
        p[jj] = pack_bf16x2(sp[(2 * jj) * H_] * s, sp[(2 * jj + 1) * H_] * s);
    *(uint4*)(Wt + (size_t)d * 8) = make_uint4(p[0], p[1], p[2], p[3]);
}

// ====================================================================
// Kernel 1: MFMA QKV projection, R15 — byte-identical codegen to the
// 140.4us best. MEASUREMENT (R19): launched 3x as SEPARATE dispatches
// (idempotent; identical compilation — unlike internal rep-loops,
// separate launches cannot perturb regalloc, the R8 lesson).
// warm_qkv = (dur - 141.3)/2 distinguishes:
//   Theory S (structure-bound): warm ~33 -> restructure next round.
//   Theory C (cold-memory-bound): warm ~14 -> qkv near floor.
// ====================================================================
struct Bfr { bf16x8 b0, b1, b2; };

__global__ __launch_bounds__(512) void qkv_mfma_k(
    const float* __restrict__ x, const unsigned short* __restrict__ Wt,
    unsigned short* __restrict__ kO, unsigned short* __restrict__ qO,
    unsigned short* __restrict__ vfO)
{
    __shared__ float4 xs[3][32][16];        // 24 KB: triple buffer, swizzled
    __shared__ unsigned short VL[32][66];   // V tile staging (pad 66)

    const int t    = threadIdx.x;           // 0..511
    const int w    = t >> 6;                // 0..7
    const int l    = t & 63;
    const int l16  = l & 15;
    const int quad = l >> 4;
    const int rg   = w >> 2;                // row-group 0..1
    const int nq   = w & 3;                 // n-quarter 0..3 (3 tiles each)
    const int row0 = blockIdx.x * 32 + rg * 16;
    const int row0b = blockIdx.x * 32;

    const int rr = w * 4 + (l >> 4);        // staged row 0..31
    const int cc = l & 15;                  // LDS chunk slot
    const int gg = cc ^ (rr & 7);           // global chunk fetched (swizzle)
    const float* gsrc = x + (size_t)(row0b + rr) * E_ + gg * 4;

    const int r  = rg * 16 + l16;           // A-frag row in tile
    const int rx = r & 7;                   // swizzle key

    // B-frag loader for iteration it (kc = it*2 and it*2+1): 6 vmem ops
    auto LB = [&](int it, Bfr& F0, Bfr& F1) {
        const unsigned short* p0 = Wt + (size_t)((it * 2) * 12 + nq * 3) * 512 + (size_t)l * 8;
        F0.b0 = *(const bf16x8*)(p0);
        F0.b1 = *(const bf16x8*)(p0 + 512);
        F0.b2 = *(const bf16x8*)(p0 + 1024);
        const unsigned short* p1 = p0 + 12 * 512;
        F1.b0 = *(const bf16x8*)(p1);
        F1.b1 = *(const bf16x8*)(p1 + 512);
        F1.b2 = *(const bf16x8*)(p1 + 1024);
    };
    // x-tile DMA for iteration it: 1 vmem op per thread
    auto DMA = [&](int it) {
        load_lds16(gsrc + it * 64, &xs[it % 3][rr][cc]);
    };

    f32x4 acc[3];
    #pragma unroll
    for (int n = 0; n < 3; n++) acc[n] = (f32x4){0.f, 0.f, 0.f, 0.f};

    Bfr Bf[2][2];                           // [parity][kk] — static after unroll
    DMA(0);                                 // oldest vmem op
    LB(0, Bf[0][0], Bf[0][1]);
    DMA(1);

    #pragma unroll
    for (int it = 0; it < 16; ++it) {
        // retire DMA(it) only; DMA(it+1) + B(it) stay in flight
        if (it == 15) asm volatile("s_waitcnt vmcnt(6)" ::: "memory");
        else          asm volatile("s_waitcnt vmcnt(7)" ::: "memory");
        __builtin_amdgcn_s_barrier();
        __builtin_amdgcn_sched_barrier(0);  // nothing hoists above barrier

        if (it + 1 < 16) LB(it + 1, Bf[(it + 1) & 1][0], Bf[(it + 1) & 1][1]);
        if (it + 2 < 16) DMA(it + 2);

        const int pc = it & 1;
        const int bsel = it % 3;
        #pragma unroll
        for (int kk = 0; kk < 2; ++kk) {
            const int G0 = kk * 8 + quad * 2;
            float4 fa = xs[bsel][r][G0 ^ rx];
            float4 fb = xs[bsel][r][(G0 + 1) ^ rx];

            union { bf16x8 v; unsigned u[4]; } av;
            av.u[0] = pack_bf16x2(fa.x, fa.y);
            av.u[1] = pack_bf16x2(fa.z, fa.w);
            av.u[2] = pack_bf16x2(fb.x, fb.y);
            av.u[3] = pack_bf16x2(fb.z, fb.w);

            Bfr& F = Bf[pc][kk];
            acc[0] = __builtin_amdgcn_mfma_f32_16x16x32_bf16(av.v, F.b0, acc[0], 0, 0, 0);
            acc[1] = __builtin_amdgcn_mfma_f32_16x16x32_bf16(av.v, F.b1, acc[1], 0, 0, 0);
            acc[2] = __builtin_amdgcn_mfma_f32_16x16x32_bf16(av.v, F.b2, acc[2], 0, 0, 0);
        }
    }

    // ---- epilogue part 1: k/q global stores, v -> LDS staging ----
    #pragma unroll
    for (int n = 0; n < 3; n++) {
        const int gn = nq * 3 + n;          // 0..11
        const int hb = gn * 16 + l16;
        if (gn < 4) {                       // k columns 0..63
            #pragma unroll
            for (int rr2 = 0; rr2 < 4; rr2++) {
                const int row = row0 + quad * 4 + rr2;
                kO[(size_t)row * H_ + hb] = bf16_rne(acc[n][rr2]);
            }
        } else if (gn < 8) {                // q columns 0..63 (pre-scaled)
            #pragma unroll
            for (int rr2 = 0; rr2 < 4; rr2++) {
                const int row = row0 + quad * 4 + rr2;
                qO[(size_t)row * H_ + (hb - 64)] = bf16_rne(acc[n][rr2]);
            }
        } else {                            // v -> LDS tile [key-in-tile][h]
            #pragma unroll
            for (int rr2 = 0; rr2 < 4; rr2++)
                VL[rg * 16 + quad * 4 + rr2][(gn - 8) * 16 + l16] = bf16_rne(acc[n][rr2]);
        }
    }
    __syncthreads();

    // ---- epilogue part 2: gather permuted frags, coalesced Vf store ----
    if (t < 256) {
        const int g  = t >> 6;          // h-group 0..3
        const int lf = t & 15;
        const int qf = (t >> 4) & 3;
        unsigned pk[4];
        #pragma unroll
        for (int jj = 0; jj < 4; jj++) {
            const int p0 = qf * 8 + 2 * jj;
            const int i0 = (p0 >> 1) | ((p0 & 1) << 4);
            const int p1 = p0 + 1;
            const int i1 = (p1 >> 1) | ((p1 & 1) << 4);
            pk[jj] = (unsigned)VL[i0][g * 16 + lf]
                   | ((unsigned)VL[i1][g * 16 + lf] << 16);
        }
        const int tile = blockIdx.x;    // = b*64 + kt
        *(uint4*)(vfO + ((size_t)tile * 4 + g) * 512 + (size_t)(t & 63) * 8) =
            make_uint4(pk[0], pk[1], pk[2], pk[3]);
    }
}

// ====================================================================
// Kernel 2: MFMA flash attention, R18 (UNCHANGED from R10's 141.3
// config). Attn levers exhausted: 8 variants all 27-35us.
// ====================================================================
struct Kfr { bf16x8 k00, k01, k10, k11; };
struct Vfr { bf16x8 v0, v1, v2, v3; };

__global__ __launch_bounds__(512, 2) void attn_mfma(
    const unsigned short* __restrict__ q,   // bf16 [B][T][H], pre-scaled
    const unsigned short* __restrict__ k,   // bf16 [B][T][H]
    const unsigned short* __restrict__ vf,  // bf16 fragment-major
    float* __restrict__ out)
{
    __shared__ unsigned short Pl[8][2][16 * 40];   // 20 KB  P double-buffer
    __shared__ float Ot[8][16][68];                // 34.8 KB merge
    __shared__ float LsW[8][16];                   // 512 B

    const int t    = threadIdx.x;       // 0..511
    const int w    = t >> 6;            // 0..7
    const int l    = t & 63;
    const int l16  = l & 15;
    const int quad = l >> 4;

    const int b  = blockIdx.x & 7;      // batch (keeps XCD pinning: blk%8)
    const int p  = blockIdx.x >> 3;     // antidiagonal pair 0..63

    const unsigned short* kbp = k  + (size_t)b * T_ * H_ + (size_t)l16 * H_ + quad * 8;
    const unsigned short* vfb = vf + (size_t)b * 64 * 2048 + (size_t)l * 8;
    unsigned short* Pw0 = &Pl[w][0][0];
    unsigned short* Pw1 = &Pl[w][1][0];

    for (int ph = 0; ph < 2; ++ph) {
        const int qt = ph ? (127 - p) : p;
        const int t0 = qt * 16;
        const int nk = t0 / 32 + 1;

        const size_t qoff = ((size_t)b * T_ + t0 + l16) * H_ + quad * 8;
        bf16x8 aq0 = *(const bf16x8*)(q + qoff);
        bf16x8 aq1 = *(const bf16x8*)(q + qoff + 32);

        f32x4 o[4];
        #pragma unroll
        for (int g = 0; g < 4; g++) o[g] = (f32x4){0.f, 0.f, 0.f, 0.f};
        float ls[4] = {0.f, 0.f, 0.f, 0.f};

        auto LK = [&](int kt, Kfr& K) {
            const unsigned short* kp = kbp + (size_t)kt * 32 * H_;
            K.k00 = *(const bf16x8*)(kp);
            K.k01 = *(const bf16x8*)(kp + 32);
            K.k10 = *(const bf16x8*)(kp + 16 * H_);
            K.k11 = *(const bf16x8*)(kp + 16 * H_ + 32);
        };
        auto LV = [&](int kt, Vfr& V) {
            const unsigned short* vp = vfb + (size_t)kt * 2048;
            V.v0 = *(const bf16x8*)(vp);
            V.v1 = *(const bf16x8*)(vp + 512);
            V.v2 = *(const bf16x8*)(vp + 1024);
            V.v3 = *(const bf16x8*)(vp + 1536);
        };
        auto QKSM = [&](int kt, const Kfr& K, unsigned short* Pw) {
            f32x4 s0 = (f32x4){0.f, 0.f, 0.f, 0.f};
            f32x4 s1 = (f32x4){0.f, 0.f, 0.f, 0.f};
            __builtin_amdgcn_s_setprio(1);
            s0 = __builtin_amdgcn_mfma_f32_16x16x32_bf16(aq0, K.k00, s0, 0, 0, 0);
            s0 = __builtin_amdgcn_mfma_f32_16x16x32_bf16(aq1, K.k01, s0, 0, 0, 0);
            s1 = __builtin_amdgcn_mfma_f32_16x16x32_bf16(aq0, K.k10, s1, 0, 0, 0);
            s1 = __builtin_amdgcn_mfma_f32_16x16x32_bf16(aq1, K.k11, s1, 0, 0, 0);
            __builtin_amdgcn_s_setprio(0);
            const int kbase = kt * 32;
            if (kbase + 31 > t0) {          // diagonal tile: causal mask
                const int rowb = t0 + quad * 4;
                #pragma unroll
                for (int r = 0; r < 4; r++) {
                    if (kbase + l16 > rowb + r)      s0[r] = -3.0e38f;
                    if (kbase + 16 + l16 > rowb + r) s1[r] = -3.0e38f;
                }
            }
            #pragma unroll
            for (int r = 0; r < 4; r++) {
                float p0 = exp2f(s0[r]);
                float p1 = exp2f(s1[r]);
                ls[r] += p0 + p1;
                *(unsigned*)(Pw + (quad * 4 + r) * 40 + 2 * l16) = pack_bf16x2(p0, p1);
            }
        };
        auto PRD = [&](const unsigned short* Pw) -> bf16x8 {
            return *(const bf16x8*)(Pw + l16 * 40 + quad * 8);
        };
        auto PV = [&](bf16x8 ap, const Vfr& V) {
            __builtin_amdgcn_s_setprio(1);
            o[0] = __builtin_amdgcn_mfma_f32_16x16x32_bf16(ap, V.v0, o[0], 0, 0, 0);
            o[1] = __builtin_amdgcn_mfma_f32_16x16x32_bf16(ap, V.v1, o[1], 0, 0, 0);
            o[2] = __builtin_amdgcn_mfma_f32_16x16x32_bf16(ap, V.v2, o[2], 0, 0, 0);
            o[3] = __builtin_amdgcn_mfma_f32_16x16x32_bf16(ap, V.v3, o[3], 0, 0, 0);
            __builtin_amdgcn_s_setprio(0);
        };

        int kt = w;                          // waves stride 8 over k-tiles
        if (kt < nk) {
            Kfr KA, KB; Vfr VA, VB;
            LK(kt, KA);
            if (kt + 8 < nk) LK(kt + 8, KB);
            LV(kt, VA);
            QKSM(kt, KA, Pw0);
            kt += 8;
            if (kt >= nk) {
                bf16x8 ap = PRD(Pw0);
                PV(ap, VA);
            } else {
                for (;;) {
                    // tile kt: K in KB; V->VB; pending PV: (Pw0, VA)
                    if (kt + 8 < nk) LK(kt + 8, KA);
                    LV(kt, VB);
                    __builtin_amdgcn_sched_barrier(0);
                    { bf16x8 ap = PRD(Pw0); QKSM(kt, KB, Pw1); PV(ap, VA); }
                    kt += 8;
                    if (kt >= nk) { bf16x8 ap = PRD(Pw1); PV(ap, VB); break; }
                    // tile kt: K in KA; V->VA; pending PV: (Pw1, VB)
                    if (kt + 8 < nk) LK(kt + 8, KB);
                    LV(kt, VA);
                    __builtin_amdgcn_sched_barrier(0);
                    { bf16x8 ap = PRD(Pw1); QKSM(kt, KA, Pw0); PV(ap, VB); }
                    kt += 8;
                    if (kt >= nk) { bf16x8 ap = PRD(Pw0); PV(ap, VA); break; }
                }
            }
        }

        // ---- per-wave lsum row reduction (16-lane groups) ----
        #pragma unroll
        for (int r = 0; r < 4; r++) {
            float s = ls[r];
            s += __shfl_xor(s, 1);
            s += __shfl_xor(s, 2);
            s += __shfl_xor(s, 4);
            s += __shfl_xor(s, 8);
            ls[r] = s;
        }

        // ---- merge across 8 waves ----
        if (l16 == 0) {
            #pragma unroll
            for (int r = 0; r < 4; r++) LsW[w][quad * 4 + r] = ls[r];
        }
        #pragma unroll
        for (int g = 0; g < 4; g++)
            #pragma unroll
            for (int r = 0; r < 4; r++)
                Ot[w][quad * 4 + r][g * 16 + l16] = o[g][r];
        __syncthreads();

        {   // 512 threads: thread (w,l) -> col l, rows w*2 + {0,1}
            const int col = l;
            #pragma unroll
            for (int rr = 0; rr < 2; ++rr) {
                const int row = w * 2 + rr;
                float L = 0.f, sv = 0.f;
                #pragma unroll
                for (int w2 = 0; w2 < 8; ++w2) {
                    L  += LsW[w2][row];
                    sv += Ot[w2][row][col];
                }
                out[((size_t)b * T_ + t0 + row) * H_ + col] = sv / L;
            }
        }
        __syncthreads();    // Ot/LsW/Pl reused by next phase
    }
}

// ====================================================================
// MEASUREMENT ROUND (R19): qkv launched 3x as separate dispatches.
// warm_qkv = (dur - 141.3)/2. Theory S (structure) -> ~33/launch ->
// dur ~207; Theory C (cold memory) -> ~14/launch -> dur ~169.
// ====================================================================
extern "C" void kernel_launch(void* const* d_in, const int* in_sizes, int n_in,
                              void* d_out, int out_size, void* d_ws, size_t ws_size,
                              hipStream_t stream)
{
    const float* x  = (const float*)d_in[0];
    const float* Wk = (const float*)d_in[1];
    const float* Wq = (const float*)d_in[2];
    const float* Wv = (const float*)d_in[3];

    // workspace: Wt (384KB) | k | q | vf (bf16, 2MB each)
    unsigned short* wt    = (unsigned short*)d_ws;
    unsigned short* kbuf  = wt + 24576 * 8;
    unsigned short* qbuf  = kbuf + BT * H_;
    unsigned short* vfbuf = qbuf + BT * H_;
    float* outp = (float*)d_out;

    wt_build_k<<<96, 256, 0, stream>>>(Wk, Wq, Wv, wt);
    for (int rep = 0; rep < 3; ++rep)
        qkv_mfma_k<<<(B_ * T_) / 32, 512, 0, stream>>>(x, wt, kbuf, qbuf, vfbuf);
    attn_mfma<<<512, 512, 0, stream>>>(qbuf, kbuf, vfbuf, outp);
}

// Round 13
// 137.430 us; speedup vs baseline: 1.3225x; 1.3225x over previous
//
#include <hip/hip_runtime.h>
#include <math.h>

// Problem constants (B,T,E,H fixed by setup_inputs).
constexpr int B_ = 8, T_ = 2048, E_ = 1024, H_ = 64;
constexpr long BT = (long)B_ * T_;   // 16384 rows

typedef __attribute__((ext_vector_type(8))) short bf16x8;   // 8 bf16 (4 VGPRs)
typedef __attribute__((ext_vector_type(4))) float f32x4;    // MFMA 16x16 acc

__device__ inline unsigned short bf16_rne(float f) {
    union { float f; unsigned u; } v; v.f = f;
    unsigned u = v.u + (0x7FFFu + ((v.u >> 16) & 1u));
    return (unsigned short)(u >> 16);
}
// HW packed fp32->bf16 RNE: 1 VALU inst vs ~6 for the bit-twiddle pair.
__device__ inline unsigned pack_bf16x2(float lo, float hi) {
    unsigned r;
    asm("v_cvt_pk_bf16_f32 %0, %1, %2" : "=v"(r) : "v"(lo), "v"(hi));
    return r;
}

// Async global->LDS DMA, 16B per lane.
__device__ inline void load_lds16(const void* g, void* l) {
    __builtin_amdgcn_global_load_lds(
        (const __attribute__((address_space(1))) void*)(uintptr_t)g,
        (__attribute__((address_space(3))) void*)(unsigned)(uintptr_t)l,
        16, 0, 0);
}

constexpr float QS = 0.18033688011112042f;   // H^-0.5 * log2(e), folded into Wq

// ====================================================================
// Kernel 0: build B-frag-ready transposed bf16 weight buffer. (R3)
// ====================================================================
__global__ __launch_bounds__(256) void wt_build_k(
    const float* __restrict__ Wk, const float* __restrict__ Wq,
    const float* __restrict__ Wv, unsigned short* __restrict__ Wt)
{
    const int d    = blockIdx.x * 256 + threadIdx.x;   // 0..24575
    const int tile = d >> 6;
    const int lq   = d & 63;
    const int quad = lq >> 4;
    const int l16  = lq & 15;
    const int kc   = tile / 12;
    const int nt   = tile - kc * 12;
    const int n    = nt * 16 + l16;

    const float* src; int col; float s = 1.0f;
    if (n < 64)       { src = Wk; col = n; }
    else if (n < 128) { src = Wq; col = n - 64; s = QS; }
    else              { src = Wv; col = n - 128; }

    const int kk0 = kc * 32 + quad * 8;
    const float* sp = src + (size_t)kk0 * H_ + col;
    unsigned p[4];
    #pragma unroll
    for (int jj = 0; jj < 4; jj++)
        p[jj] = pack_bf16x2(sp[(2 * jj) * H_] * s, sp[(2 * jj + 1) * H_] * s);
    *(uint4*)(Wt + (size_t)d * 8) = make_uint4(p[0], p[1], p[2], p[3]);
}

// ====================================================================
// Kernel 1: MFMA QKV projection, R20 (RESUBMIT — R12 bench was an
// infra failure, no measurement): B-fragments staged through LDS.
// R19 measured warm qkv = 20.2us vs ~12us model floor; the identified
// waste is 2x-redundant Wt L2 reads (waves 0-3 and 4-7 load identical
// frags; 512 blocks x 768 KB = 393 MB). Now each block DMAs its 24
// Wt tiles (24 KB/iter) ONCE via global_load_lds (3 contiguous ops/
// thread), all waves ds_read from LDS -> 197 MB (-5.7us floor) and
// ~48 B-frag VGPRs freed. x keeps depth-2 triple-buffer; B depth-1
// double-buffer (L2 latency ~250cy hides under ~600cy compute).
// Per-iter vmem ledger: outstanding on entry = X(it), B(it)x3, X(it+1)
// -> vmcnt(1) retires X(it)+B(it)x3 (it=15: vmcnt(0)). Per-wave vmcnt
// precedes s_barrier -> all waves' LDS writes visible after barrier.
// Buffer parities disjoint (compute reads Bl[it&1], DMA writes
// Bl[(it+1)&1]; xs read it%3, written (it+2)%3).
// LDS: 24 (xs) + 48 (Bl) + 4.2 (VL) = 76.2 KB -> 2 blocks/CU.
// Hang audit (R12 post-mortem): barriers/waits thread-uniform; DMA
// dests decompose to wave-uniform base + lane*16. No defect found.
// ====================================================================
__global__ __launch_bounds__(512) void qkv_mfma_k(
    const float* __restrict__ x, const unsigned short* __restrict__ Wt,
    unsigned short* __restrict__ kO, unsigned short* __restrict__ qO,
    unsigned short* __restrict__ vfO)
{
    __shared__ float4 xs[3][32][16];          // 24 KB: x triple buffer
    __shared__ unsigned short Bl[2][24][512]; // 48 KB: B double buffer
    __shared__ unsigned short VL[32][66];     // V tile staging (pad 66)

    const int t    = threadIdx.x;           // 0..511
    const int w    = t >> 6;                // 0..7
    const int l    = t & 63;
    const int l16  = l & 15;
    const int quad = l >> 4;
    const int rg   = w >> 2;                // row-group 0..1
    const int nq   = w & 3;                 // n-quarter 0..3 (3 tiles each)
    const int row0 = blockIdx.x * 32 + rg * 16;
    const int row0b = blockIdx.x * 32;

    const int rr = w * 4 + (l >> 4);        // staged row 0..31
    const int cc = l & 15;                  // LDS chunk slot
    const int gg = cc ^ (rr & 7);           // global chunk fetched (swizzle)
    const float* gsrc = x + (size_t)(row0b + rr) * E_ + gg * 4;

    const int r  = rg * 16 + l16;           // A-frag row in tile
    const int rx = r & 7;                   // swizzle key

    // B staging for iteration it: tiles it*24 + tw, tw = o*8 + w.
    // Wt layout is [kc][12 tiles] -> tile index it*24+tw is contiguous.
    auto DMAB = [&](int it) {
        const unsigned short* src = Wt + (size_t)(it * 24) * 512 + l * 8;
        #pragma unroll
        for (int o = 0; o < 3; ++o) {
            const int tw = o * 8 + w;
            load_lds16(src + (size_t)tw * 512, &Bl[it & 1][tw][l * 8]);
        }
    };
    // x-tile DMA for iteration it: 1 vmem op per thread
    auto DMAX = [&](int it) {
        load_lds16(gsrc + it * 64, &xs[it % 3][rr][cc]);
    };

    f32x4 acc[3];
    #pragma unroll
    for (int n = 0; n < 3; n++) acc[n] = (f32x4){0.f, 0.f, 0.f, 0.f};

    DMAX(0);        // oldest
    DMAB(0);        // +3
    DMAX(1);        // +1 -> 5 outstanding

    #pragma unroll
    for (int it = 0; it < 16; ++it) {
        // retire X(it) + B(it)x3, keep X(it+1) in flight
        if (it == 15) asm volatile("s_waitcnt vmcnt(0)" ::: "memory");
        else          asm volatile("s_waitcnt vmcnt(1)" ::: "memory");
        __builtin_amdgcn_s_barrier();
        __builtin_amdgcn_sched_barrier(0);  // nothing crosses the barrier

        if (it + 1 < 16) DMAB(it + 1);
        if (it + 2 < 16) DMAX(it + 2);

        const int bsel = it % 3;
        const int bb   = it & 1;
        #pragma unroll
        for (int kk = 0; kk < 2; ++kk) {
            const int G0 = kk * 8 + quad * 2;
            float4 fa = xs[bsel][r][G0 ^ rx];
            float4 fb = xs[bsel][r][(G0 + 1) ^ rx];

            const unsigned short* bp = &Bl[bb][kk * 12 + nq * 3][0] + l * 8;
            bf16x8 b0 = *(const bf16x8*)(bp);
            bf16x8 b1 = *(const bf16x8*)(bp + 512);
            bf16x8 b2 = *(const bf16x8*)(bp + 1024);

            union { bf16x8 v; unsigned u[4]; } av;
            av.u[0] = pack_bf16x2(fa.x, fa.y);
            av.u[1] = pack_bf16x2(fa.z, fa.w);
            av.u[2] = pack_bf16x2(fb.x, fb.y);
            av.u[3] = pack_bf16x2(fb.z, fb.w);

            acc[0] = __builtin_amdgcn_mfma_f32_16x16x32_bf16(av.v, b0, acc[0], 0, 0, 0);
            acc[1] = __builtin_amdgcn_mfma_f32_16x16x32_bf16(av.v, b1, acc[1], 0, 0, 0);
            acc[2] = __builtin_amdgcn_mfma_f32_16x16x32_bf16(av.v, b2, acc[2], 0, 0, 0);
        }
    }

    // ---- epilogue part 1: k/q global stores, v -> LDS staging ----
    #pragma unroll
    for (int n = 0; n < 3; n++) {
        const int gn = nq * 3 + n;          // 0..11
        const int hb = gn * 16 + l16;
        if (gn < 4) {                       // k columns 0..63
            #pragma unroll
            for (int rr2 = 0; rr2 < 4; rr2++) {
                const int row = row0 + quad * 4 + rr2;
                kO[(size_t)row * H_ + hb] = bf16_rne(acc[n][rr2]);
            }
        } else if (gn < 8) {                // q columns 0..63 (pre-scaled)
            #pragma unroll
            for (int rr2 = 0; rr2 < 4; rr2++) {
                const int row = row0 + quad * 4 + rr2;
                qO[(size_t)row * H_ + (hb - 64)] = bf16_rne(acc[n][rr2]);
            }
        } else {                            // v -> LDS tile [key-in-tile][h]
            #pragma unroll
            for (int rr2 = 0; rr2 < 4; rr2++)
                VL[rg * 16 + quad * 4 + rr2][(gn - 8) * 16 + l16] = bf16_rne(acc[n][rr2]);
        }
    }
    __syncthreads();

    // ---- epilogue part 2: gather permuted frags, coalesced Vf store ----
    if (t < 256) {
        const int g  = t >> 6;          // h-group 0..3
        const int lf = t & 15;
        const int qf = (t >> 4) & 3;
        unsigned pk[4];
        #pragma unroll
        for (int jj = 0; jj < 4; jj++) {
            const int p0 = qf * 8 + 2 * jj;
            const int i0 = (p0 >> 1) | ((p0 & 1) << 4);
            const int p1 = p0 + 1;
            const int i1 = (p1 >> 1) | ((p1 & 1) << 4);
            pk[jj] = (unsigned)VL[i0][g * 16 + lf]
                   | ((unsigned)VL[i1][g * 16 + lf] << 16);
        }
        const int tile = blockIdx.x;    // = b*64 + kt
        *(uint4*)(vfO + ((size_t)tile * 4 + g) * 512 + (size_t)(t & 63) * 8) =
            make_uint4(pk[0], pk[1], pk[2], pk[3]);
    }
}

// ====================================================================
// Kernel 2: MFMA flash attention — exact R14 of the 140.4us best
// (plain launch_bounds(512), no setprio; R10's setprio/(512,2) was
// +0.9us = noise). Attn levers exhausted: 8 variants all 27-35us.
// ====================================================================
struct Kfr { bf16x8 k00, k01, k10, k11; };
struct Vfr { bf16x8 v0, v1, v2, v3; };

__global__ __launch_bounds__(512) void attn_mfma(
    const unsigned short* __restrict__ q,   // bf16 [B][T][H], pre-scaled
    const unsigned short* __restrict__ k,   // bf16 [B][T][H]
    const unsigned short* __restrict__ vf,  // bf16 fragment-major
    float* __restrict__ out)
{
    __shared__ unsigned short Pl[8][2][16 * 40];   // 20 KB  P double-buffer
    __shared__ float Ot[8][16][68];                // 34.8 KB merge
    __shared__ float LsW[8][16];                   // 512 B

    const int t    = threadIdx.x;       // 0..511
    const int w    = t >> 6;            // 0..7
    const int l    = t & 63;
    const int l16  = l & 15;
    const int quad = l >> 4;

    const int b  = blockIdx.x & 7;      // batch (keeps XCD pinning: blk%8)
    const int p  = blockIdx.x >> 3;     // antidiagonal pair 0..63

    const unsigned short* kbp = k  + (size_t)b * T_ * H_ + (size_t)l16 * H_ + quad * 8;
    const unsigned short* vfb = vf + (size_t)b * 64 * 2048 + (size_t)l * 8;
    unsigned short* Pw0 = &Pl[w][0][0];
    unsigned short* Pw1 = &Pl[w][1][0];

    for (int ph = 0; ph < 2; ++ph) {
        const int qt = ph ? (127 - p) : p;
        const int t0 = qt * 16;
        const int nk = t0 / 32 + 1;

        const size_t qoff = ((size_t)b * T_ + t0 + l16) * H_ + quad * 8;
        bf16x8 aq0 = *(const bf16x8*)(q + qoff);
        bf16x8 aq1 = *(const bf16x8*)(q + qoff + 32);

        f32x4 o[4];
        #pragma unroll
        for (int g = 0; g < 4; g++) o[g] = (f32x4){0.f, 0.f, 0.f, 0.f};
        float ls[4] = {0.f, 0.f, 0.f, 0.f};

        auto LK = [&](int kt, Kfr& K) {
            const unsigned short* kp = kbp + (size_t)kt * 32 * H_;
            K.k00 = *(const bf16x8*)(kp);
            K.k01 = *(const bf16x8*)(kp + 32);
            K.k10 = *(const bf16x8*)(kp + 16 * H_);
            K.k11 = *(const bf16x8*)(kp + 16 * H_ + 32);
        };
        auto LV = [&](int kt, Vfr& V) {
            const unsigned short* vp = vfb + (size_t)kt * 2048;
            V.v0 = *(const bf16x8*)(vp);
            V.v1 = *(const bf16x8*)(vp + 512);
            V.v2 = *(const bf16x8*)(vp + 1024);
            V.v3 = *(const bf16x8*)(vp + 1536);
        };
        auto QKSM = [&](int kt, const Kfr& K, unsigned short* Pw) {
            f32x4 s0 = (f32x4){0.f, 0.f, 0.f, 0.f};
            f32x4 s1 = (f32x4){0.f, 0.f, 0.f, 0.f};
            s0 = __builtin_amdgcn_mfma_f32_16x16x32_bf16(aq0, K.k00, s0, 0, 0, 0);
            s0 = __builtin_amdgcn_mfma_f32_16x16x32_bf16(aq1, K.k01, s0, 0, 0, 0);
            s1 = __builtin_amdgcn_mfma_f32_16x16x32_bf16(aq0, K.k10, s1, 0, 0, 0);
            s1 = __builtin_amdgcn_mfma_f32_16x16x32_bf16(aq1, K.k11, s1, 0, 0, 0);
            const int kbase = kt * 32;
            if (kbase + 31 > t0) {          // diagonal tile: causal mask
                const int rowb = t0 + quad * 4;
                #pragma unroll
                for (int r = 0; r < 4; r++) {
                    if (kbase + l16 > rowb + r)      s0[r] = -3.0e38f;
                    if (kbase + 16 + l16 > rowb + r) s1[r] = -3.0e38f;
                }
            }
            #pragma unroll
            for (int r = 0; r < 4; r++) {
                float p0 = exp2f(s0[r]);
                float p1 = exp2f(s1[r]);
                ls[r] += p0 + p1;
                *(unsigned*)(Pw + (quad * 4 + r) * 40 + 2 * l16) = pack_bf16x2(p0, p1);
            }
        };
        auto PRD = [&](const unsigned short* Pw) -> bf16x8 {
            return *(const bf16x8*)(Pw + l16 * 40 + quad * 8);
        };
        auto PV = [&](bf16x8 ap, const Vfr& V) {
            o[0] = __builtin_amdgcn_mfma_f32_16x16x32_bf16(ap, V.v0, o[0], 0, 0, 0);
            o[1] = __builtin_amdgcn_mfma_f32_16x16x32_bf16(ap, V.v1, o[1], 0, 0, 0);
            o[2] = __builtin_amdgcn_mfma_f32_16x16x32_bf16(ap, V.v2, o[2], 0, 0, 0);
            o[3] = __builtin_amdgcn_mfma_f32_16x16x32_bf16(ap, V.v3, o[3], 0, 0, 0);
        };

        int kt = w;                          // waves stride 8 over k-tiles
        if (kt < nk) {
            Kfr KA, KB; Vfr VA, VB;
            LK(kt, KA);
            if (kt + 8 < nk) LK(kt + 8, KB);
            LV(kt, VA);
            QKSM(kt, KA, Pw0);
            kt += 8;
            if (kt >= nk) {
                bf16x8 ap = PRD(Pw0);
                PV(ap, VA);
            } else {
                for (;;) {
                    // tile kt: K in KB; V->VB; pending PV: (Pw0, VA)
                    if (kt + 8 < nk) LK(kt + 8, KA);
                    LV(kt, VB);
                    __builtin_amdgcn_sched_barrier(0);
                    { bf16x8 ap = PRD(Pw0); QKSM(kt, KB, Pw1); PV(ap, VA); }
                    kt += 8;
                    if (kt >= nk) { bf16x8 ap = PRD(Pw1); PV(ap, VB); break; }
                    // tile kt: K in KA; V->VA; pending PV: (Pw1, VB)
                    if (kt + 8 < nk) LK(kt + 8, KB);
                    LV(kt, VA);
                    __builtin_amdgcn_sched_barrier(0);
                    { bf16x8 ap = PRD(Pw1); QKSM(kt, KA, Pw0); PV(ap, VB); }
                    kt += 8;
                    if (kt >= nk) { bf16x8 ap = PRD(Pw0); PV(ap, VA); break; }
                }
            }
        }

        // ---- per-wave lsum row reduction (16-lane groups) ----
        #pragma unroll
        for (int r = 0; r < 4; r++) {
            float s = ls[r];
            s += __shfl_xor(s, 1);
            s += __shfl_xor(s, 2);
            s += __shfl_xor(s, 4);
            s += __shfl_xor(s, 8);
            ls[r] = s;
        }

        // ---- merge across 8 waves ----
        if (l16 == 0) {
            #pragma unroll
            for (int r = 0; r < 4; r++) LsW[w][quad * 4 + r] = ls[r];
        }
        #pragma unroll
        for (int g = 0; g < 4; g++)
            #pragma unroll
            for (int r = 0; r < 4; r++)
                Ot[w][quad * 4 + r][g * 16 + l16] = o[g][r];
        __syncthreads();

        {   // 512 threads: thread (w,l) -> col l, rows w*2 + {0,1}
            const int col = l;
            #pragma unroll
            for (int rr = 0; rr < 2; ++rr) {
                const int row = w * 2 + rr;
                float L = 0.f, sv = 0.f;
                #pragma unroll
                for (int w2 = 0; w2 < 8; ++w2) {
                    L  += LsW[w2][row];
                    sv += Ot[w2][row][col];
                }
                out[((size_t)b * T_ + t0 + row) * H_ + col] = sv / L;
            }
        }
        __syncthreads();    // Ot/LsW/Pl reused by next phase
    }
}

// ====================================================================
extern "C" void kernel_launch(void* const* d_in, const int* in_sizes, int n_in,
                              void* d_out, int out_size, void* d_ws, size_t ws_size,
                              hipStream_t stream)
{
    const float* x  = (const float*)d_in[0];
    const float* Wk = (const float*)d_in[1];
    const float* Wq = (const float*)d_in[2];
    const float* Wv = (const float*)d_in[3];

    // workspace: Wt (384KB) | k | q | vf (bf16, 2MB each)
    unsigned short* wt    = (unsigned short*)d_ws;
    unsigned short* kbuf  = wt + 24576 * 8;
    unsigned short* qbuf  = kbuf + BT * H_;
    unsigned short* vfbuf = qbuf + BT * H_;
    float* outp = (float*)d_out;

    wt_build_k<<<96, 256, 0, stream>>>(Wk, Wq, Wv, wt);
    qkv_mfma_k<<<(B_ * T_) / 32, 512, 0, stream>>>(x, wt, kbuf, qbuf, vfbuf);
    attn_mfma<<<512, 512, 0, stream>>>(qbuf, kbuf, vfbuf, outp);
}